// Round 1
// baseline (645.620 us; speedup 1.0000x reference)
//
#include <hip/hip_runtime.h>
#include <math.h>

#define M_ROWS 1536
#define NC 96
#define KG 16
#define FD 8192
#define DL 1024
#define NS 8
#define NSPLIT 8
#define KC (FD / NSPLIT)   /* 1024 */
#define NT 32              /* n-tile of GEMM */
#define KB 32              /* staged k per iteration */
#define AST 40             /* A LDS row stride (floats, 16B aligned) */
#define BST 40             /* B LDS row stride */
#define MARGIN 0.3f

// ---------------- K1: centers + squared-norm partials ----------------
// grid (96, 4), block 256. Block (c, bd) handles d-range [bd*2048, bd*2048+2048)
__global__ void centers_kernel(const float* __restrict__ feats,
                               float* __restrict__ centers,
                               float* __restrict__ fnp,   // [4][1536] feat-row sq partials
                               float* __restrict__ cnp) { // [4][96]  center sq partials
    const int c = blockIdx.x;
    const int bd = blockIdx.y;
    const int tid = threadIdx.x;

    float sq[KG];
#pragma unroll
    for (int k = 0; k < KG; ++k) sq[k] = 0.f;
    float cp = 0.f;

#pragma unroll
    for (int it = 0; it < 2; ++it) {
        const int base = bd * 2048 + it * 1024 + tid * 4;
        float4 acc = make_float4(0.f, 0.f, 0.f, 0.f);
#pragma unroll
        for (int k = 0; k < KG; ++k) {
            const float4 v = *(const float4*)&feats[(size_t)(c * KG + k) * FD + base];
            acc.x += v.x; acc.y += v.y; acc.z += v.z; acc.w += v.w;
            sq[k] += v.x * v.x + v.y * v.y + v.z * v.z + v.w * v.w;
        }
        float4 cv = make_float4(acc.x * 0.0625f, acc.y * 0.0625f,
                                acc.z * 0.0625f, acc.w * 0.0625f);
        *(float4*)&centers[(size_t)c * FD + base] = cv;
        cp += cv.x * cv.x + cv.y * cv.y + cv.z * cv.z + cv.w * cv.w;
    }

    // wave reduce (64-wide), then cross-wave via LDS
    const int lane = tid & 63;
    const int w = tid >> 6;
    __shared__ float wred[4][17];
#pragma unroll
    for (int k = 0; k < KG; ++k) {
        float v = sq[k];
#pragma unroll
        for (int off = 32; off > 0; off >>= 1) v += __shfl_down(v, off, 64);
        if (lane == 0) wred[w][k] = v;
    }
    {
        float v = cp;
#pragma unroll
        for (int off = 32; off > 0; off >>= 1) v += __shfl_down(v, off, 64);
        if (lane == 0) wred[w][16] = v;
    }
    __syncthreads();
    if (tid < 17) {
        const float t = wred[0][tid] + wred[1][tid] + wred[2][tid] + wred[3][tid];
        if (tid < 16) fnp[bd * M_ROWS + c * KG + tid] = t;
        else          cnp[bd * NC + c] = t;
    }
}

// ---------------- K2: dot(center, feat) partial GEMM ----------------
// grid (48, 8): bx = 32-col tile, by = 1024-k chunk. block 256.
__global__ void gemm_part_kernel(const float* __restrict__ centers,
                                 const float* __restrict__ feats,
                                 float* __restrict__ part) { // [8][96][1536]
    const int bx = blockIdx.x;
    const int by = blockIdx.y;
    const int tid = threadIdx.x;
    __shared__ float alds[NC * AST];
    __shared__ float blds[NT * BST];

    const int j0 = bx * NT;
    const int k0base = by * KC;
    const int mg = tid >> 4;      // 0..15
    const int np = tid & 15;      // 0..15
    const int m0 = mg * 6;

    float acc[6][2];
#pragma unroll
    for (int a = 0; a < 6; ++a) { acc[a][0] = 0.f; acc[a][1] = 0.f; }

    for (int st = 0; st < KC / KB; ++st) {
        const int k0 = k0base + st * KB;
        // stage A: 96x32 floats = 768 float4, 3 per thread
#pragma unroll
        for (int i = 0; i < 3; ++i) {
            const int q = tid + i * 256;
            const int m = q >> 3, kk = (q & 7) * 4;
            const float4 v = *(const float4*)&centers[(size_t)m * FD + k0 + kk];
            *(float4*)&alds[m * AST + kk] = v;
        }
        // stage B: 32x32 floats = 256 float4, 1 per thread
        {
            const int n = tid >> 3, kk = (tid & 7) * 4;
            const float4 v = *(const float4*)&feats[(size_t)(j0 + n) * FD + k0 + kk];
            *(float4*)&blds[n * BST + kk] = v;
        }
        __syncthreads();
#pragma unroll
        for (int kk4 = 0; kk4 < KB; kk4 += 4) {
            const float4 b0 = *(const float4*)&blds[np * BST + kk4];
            const float4 b1 = *(const float4*)&blds[(np + 16) * BST + kk4];
#pragma unroll
            for (int mi = 0; mi < 6; ++mi) {
                const float4 a = *(const float4*)&alds[(m0 + mi) * AST + kk4];
                acc[mi][0] += a.x * b0.x + a.y * b0.y + a.z * b0.z + a.w * b0.w;
                acc[mi][1] += a.x * b1.x + a.y * b1.y + a.z * b1.z + a.w * b1.w;
            }
        }
        __syncthreads();
    }

    float* pp = part + (size_t)by * NC * M_ROWS;
#pragma unroll
    for (int mi = 0; mi < 6; ++mi) {
        pp[(m0 + mi) * M_ROWS + j0 + np]      = acc[mi][0];
        pp[(m0 + mi) * M_ROWS + j0 + np + 16] = acc[mi][1];
    }
}

// ---------------- K3: finalize d2 + masked argmax/argmin ----------------
// grid 96, block 256
__global__ void select_kernel(const float* __restrict__ part,
                              const float* __restrict__ fnp,
                              const float* __restrict__ cnp,
                              const int* __restrict__ labels,
                              int* __restrict__ pinds,
                              int* __restrict__ ninds) {
    const int c = blockIdx.x;
    const int tid = threadIdx.x;
    const int anchor = labels[c * KG];

    float cn = 0.f;
#pragma unroll
    for (int b = 0; b < 4; ++b) cn += cnp[b * NC + c];

    float bestp = -INFINITY; int bpi = 1 << 30;
    float bestn =  INFINITY; int bni = 1 << 30;

    for (int j = tid; j < M_ROWS; j += 256) {
        float dot = 0.f;
#pragma unroll
        for (int p = 0; p < NSPLIT; ++p)
            dot += part[(size_t)p * NC * M_ROWS + c * M_ROWS + j];
        float fn = 0.f;
#pragma unroll
        for (int b = 0; b < 4; ++b) fn += fnp[b * M_ROWS + j];
        const float d2 = cn + fn - 2.f * dot;
        const bool pos = (labels[j] == anchor);
        if (pos) {
            if (d2 > bestp || (d2 == bestp && j < bpi)) { bestp = d2; bpi = j; }
        } else {
            if (d2 < bestn || (d2 == bestn && j < bni)) { bestn = d2; bni = j; }
        }
    }

    __shared__ float sv[256];
    __shared__ int   si[256];
    // argmax (first index on tie)
    sv[tid] = bestp; si[tid] = bpi; __syncthreads();
    for (int s = 128; s > 0; s >>= 1) {
        if (tid < s) {
            if (sv[tid + s] > sv[tid] ||
                (sv[tid + s] == sv[tid] && si[tid + s] < si[tid])) {
                sv[tid] = sv[tid + s]; si[tid] = si[tid + s];
            }
        }
        __syncthreads();
    }
    if (tid == 0) pinds[c] = si[0];
    __syncthreads();
    // argmin
    sv[tid] = bestn; si[tid] = bni; __syncthreads();
    for (int s = 128; s > 0; s >>= 1) {
        if (tid < s) {
            if (sv[tid + s] < sv[tid] ||
                (sv[tid + s] == sv[tid] && si[tid + s] < si[tid])) {
                sv[tid] = sv[tid + s]; si[tid] = si[tid + s];
            }
        }
        __syncthreads();
    }
    if (tid == 0) ninds[c] = si[0];
}

// ---------------- K4: local stripe distances + DP ----------------
// grid (96, 2): by==0 -> hardest positive, by==1 -> hardest negative
__global__ void local_kernel(const float* __restrict__ centers,
                             const float* __restrict__ localf,
                             const int* __restrict__ pinds,
                             const int* __restrict__ ninds,
                             float* __restrict__ res) { // [2][96]
    const int c = blockIdx.x;
    const int which = blockIdx.y;
    const int tid = threadIdx.x;
    const int idx = (which == 0) ? pinds[c] : ninds[c];

    __shared__ float xl[NS * 1028];
    __shared__ float yl[NS * 1032];
    __shared__ float sred[256];
    __shared__ float dmat[64];
    __shared__ float xx[8], yy[8], xyv[64];

    // stage x (centers row c as 8x1024) and y (localf row idx, transposed)
#pragma unroll
    for (int it = 0; it < 8; ++it) {
        const int q = tid + it * 256;
        const float4 v = *(const float4*)&centers[(size_t)c * FD + q * 4];
        const int i = q >> 8;             // stripe
        const int d = (q * 4) & 1023;     // offset in stripe
        *(float4*)&xl[i * 1028 + d] = v;

        const float4 w = *(const float4*)&localf[(size_t)idx * FD + q * 4];
        const int jb = (q * 4) & 7;       // 0 or 4
        const int dd = q >> 1;            // local dim
        yl[(jb + 0) * 1032 + dd] = w.x;
        yl[(jb + 1) * 1032 + dd] = w.y;
        yl[(jb + 2) * 1032 + dd] = w.z;
        yl[(jb + 3) * 1032 + dd] = w.w;
    }
    __syncthreads();

    // 64 cross dots, 4 threads each (interleaved d to spread banks)
    const int p = tid >> 2, c4 = tid & 3;
    const int i = p >> 3, j = p & 7;
    float s = 0.f;
    for (int t = 0; t < 64; ++t) {
        const int d = c4 * 4 + t * 16;
        const float4 xv = *(const float4*)&xl[i * 1028 + d];
        const float4 yv = *(const float4*)&yl[j * 1032 + d];
        s += xv.x * yv.x + xv.y * yv.y + xv.z * yv.z + xv.w * yv.w;
    }
    sred[tid] = s;
    __syncthreads();
    if (tid < 64)
        xyv[tid] = sred[tid * 4] + sred[tid * 4 + 1] + sred[tid * 4 + 2] + sred[tid * 4 + 3];

    // 16 self dots (8 xx, 8 yy), threads 0..63, 4 per reduction
    float s2 = 0.f;
    if (tid < 64) {
        const int r = tid >> 2;
        const float* base = (r < 8) ? &xl[r * 1028] : &yl[(r - 8) * 1032];
        for (int t = 0; t < 64; ++t) {
            const int d = c4 * 4 + t * 16;
            const float4 v = *(const float4*)&base[d];
            s2 += v.x * v.x + v.y * v.y + v.z * v.z + v.w * v.w;
        }
    }
    __syncthreads();
    sred[tid] = s2;
    __syncthreads();
    if (tid < 16) {
        const float v = sred[tid * 4] + sred[tid * 4 + 1] + sred[tid * 4 + 2] + sred[tid * 4 + 3];
        if (tid < 8) xx[tid] = v; else yy[tid - 8] = v;
    }
    __syncthreads();

    if (tid < 64) {
        const float d2 = xx[i] + yy[j] - 2.f * xyv[tid];
        const float d = sqrtf(fmaxf(d2, 1e-12f));
        dmat[tid] = tanhf(0.5f * d);   // == (e^d - 1)/(e^d + 1)
    }
    __syncthreads();

    if (tid == 0) {
        float prev[8], cur[8];
        cur[0] = dmat[0];
#pragma unroll
        for (int jj = 1; jj < 8; ++jj) cur[jj] = cur[jj - 1] + dmat[jj];
        for (int ii = 1; ii < 8; ++ii) {
#pragma unroll
            for (int jj = 0; jj < 8; ++jj) prev[jj] = cur[jj];
            cur[0] = prev[0] + dmat[ii * 8];
#pragma unroll
            for (int jj = 1; jj < 8; ++jj)
                cur[jj] = fminf(prev[jj], cur[jj - 1]) + dmat[ii * 8 + jj];
        }
        res[which * NC + c] = cur[7];
    }
}

// ---------------- K5: mean(relu(ap - an + margin)) ----------------
__global__ void loss_kernel(const float* __restrict__ res, float* __restrict__ out) {
    const int tid = threadIdx.x; // 128
    float v = 0.f;
    if (tid < NC) v = fmaxf(res[tid] - res[NC + tid] + MARGIN, 0.f);
#pragma unroll
    for (int off = 32; off > 0; off >>= 1) v += __shfl_down(v, off, 64);
    __shared__ float w2[2];
    const int lane = tid & 63, w = tid >> 6;
    if (lane == 0) w2[w] = v;
    __syncthreads();
    if (tid == 0) out[0] = (w2[0] + w2[1]) * (1.f / NC);
}

extern "C" void kernel_launch(void* const* d_in, const int* in_sizes, int n_in,
                              void* d_out, int out_size, void* d_ws, size_t ws_size,
                              hipStream_t stream) {
    const float* feats  = (const float*)d_in[0];
    const int*   labels = (const int*)d_in[1];
    const float* localf = (const float*)d_in[2];
    float* out = (float*)d_out;

    float* centers = (float*)d_ws;                         // 96*8192
    float* part    = centers + (size_t)NC * FD;            // 8*96*1536
    float* fnp     = part + (size_t)NSPLIT * NC * M_ROWS;  // 4*1536
    float* cnp     = fnp + 4 * M_ROWS;                     // 4*96
    float* res     = cnp + 4 * NC;                         // 2*96
    int*   pinds   = (int*)(res + 2 * NC);                 // 96
    int*   ninds   = pinds + NC;                           // 96

    hipLaunchKernelGGL(centers_kernel, dim3(NC, 4), dim3(256), 0, stream,
                       feats, centers, fnp, cnp);
    hipLaunchKernelGGL(gemm_part_kernel, dim3(M_ROWS / NT, NSPLIT), dim3(256), 0, stream,
                       centers, feats, part);
    hipLaunchKernelGGL(select_kernel, dim3(NC), dim3(256), 0, stream,
                       part, fnp, cnp, labels, pinds, ninds);
    hipLaunchKernelGGL(local_kernel, dim3(NC, 2), dim3(256), 0, stream,
                       centers, localf, pinds, ninds, res);
    hipLaunchKernelGGL(loss_kernel, dim3(1), dim3(128), 0, stream, res, out);
}

// Round 2
// 194.954 us; speedup vs baseline: 3.3117x; 3.3117x over previous
//
#include <hip/hip_runtime.h>
#include <math.h>

#define M_ROWS 1536
#define NC 96
#define KG 16
#define FD 8192
#define NS 8
#define MARGIN 0.3f

#define KSPLIT 32
#define KCH 256            /* k per block */
#define BKS 32             /* k per stage */
#define BN2 64
#define AST2 36            /* padded LDS strides (floats) */
#define BST2 36

// ---------------- K1: centers + squared-norm partials ----------------
__global__ void centers_kernel(const float* __restrict__ feats,
                               float* __restrict__ centers,
                               float* __restrict__ fnp,   // [4][1536]
                               float* __restrict__ cnp) { // [4][96]
    const int c = blockIdx.x;
    const int bd = blockIdx.y;
    const int tid = threadIdx.x;

    float sq[KG];
#pragma unroll
    for (int k = 0; k < KG; ++k) sq[k] = 0.f;
    float cp = 0.f;

#pragma unroll
    for (int it = 0; it < 2; ++it) {
        const int base = bd * 2048 + it * 1024 + tid * 4;
        float4 acc = make_float4(0.f, 0.f, 0.f, 0.f);
#pragma unroll
        for (int k = 0; k < KG; ++k) {
            const float4 v = *(const float4*)&feats[(size_t)(c * KG + k) * FD + base];
            acc.x += v.x; acc.y += v.y; acc.z += v.z; acc.w += v.w;
            sq[k] += v.x * v.x + v.y * v.y + v.z * v.z + v.w * v.w;
        }
        float4 cv = make_float4(acc.x * 0.0625f, acc.y * 0.0625f,
                                acc.z * 0.0625f, acc.w * 0.0625f);
        *(float4*)&centers[(size_t)c * FD + base] = cv;
        cp += cv.x * cv.x + cv.y * cv.y + cv.z * cv.z + cv.w * cv.w;
    }

    const int lane = tid & 63;
    const int w = tid >> 6;
    __shared__ float wred[4][17];
#pragma unroll
    for (int k = 0; k < KG; ++k) {
        float v = sq[k];
#pragma unroll
        for (int off = 32; off > 0; off >>= 1) v += __shfl_down(v, off, 64);
        if (lane == 0) wred[w][k] = v;
    }
    {
        float v = cp;
#pragma unroll
        for (int off = 32; off > 0; off >>= 1) v += __shfl_down(v, off, 64);
        if (lane == 0) wred[w][16] = v;
    }
    __syncthreads();
    if (tid < 17) {
        const float t = wred[0][tid] + wred[1][tid] + wred[2][tid] + wred[3][tid];
        if (tid < 16) fnp[bd * M_ROWS + c * KG + tid] = t;
        else          cnp[bd * NC + c] = t;
    }
}

// ---------------- K2: dot(center, feat) partial GEMM ----------------
// 768 blocks of 128 threads. by = k-split (0..31), bx = n-tile (0..23).
// by = blockIdx.x & 31 so rawid%8 == by%8 -> same k-slice pins to one XCD L2.
__global__ __launch_bounds__(128) void gemm2_kernel(const float* __restrict__ centers,
                                                    const float* __restrict__ feats,
                                                    float* __restrict__ part) { // [96][32][1536]
    const int by = blockIdx.x & 31;
    const int bx = blockIdx.x >> 5;
    const int tid = threadIdx.x;

    __shared__ float alds[NC * AST2];
    __shared__ float blds[BN2 * BST2];

    const int j0 = bx * BN2;
    const int k0b = by * KCH;

    const int tx = tid & 7;          // n = tx + 8*nn
    const int ty = tid >> 3;         // m = ty*6 + mi
    const int m0 = ty * 6;

    float acc[6][8];
#pragma unroll
    for (int a = 0; a < 6; ++a)
#pragma unroll
        for (int b = 0; b < 8; ++b) acc[a][b] = 0.f;

    for (int st = 0; st < KCH / BKS; ++st) {
        const int k0 = k0b + st * BKS;
        // stage A: 96x32 floats = 768 float4, 6 per thread
#pragma unroll
        for (int i = 0; i < 6; ++i) {
            const int q = tid + i * 128;
            const int m = q >> 3, kk = (q & 7) * 4;
            *(float4*)&alds[m * AST2 + kk] =
                *(const float4*)&centers[(size_t)m * FD + k0 + kk];
        }
        // stage B: 64x32 floats = 512 float4, 4 per thread
#pragma unroll
        for (int i = 0; i < 4; ++i) {
            const int q = tid + i * 128;
            const int n = q >> 3, kk = (q & 7) * 4;
            *(float4*)&blds[n * BST2 + kk] =
                *(const float4*)&feats[(size_t)(j0 + n) * FD + k0 + kk];
        }
        __syncthreads();
#pragma unroll
        for (int kk4 = 0; kk4 < BKS; kk4 += 4) {
            float4 bv[8];
#pragma unroll
            for (int nn = 0; nn < 8; ++nn)
                bv[nn] = *(const float4*)&blds[(tx + nn * 8) * BST2 + kk4];
            float4 av[6];
#pragma unroll
            for (int mi = 0; mi < 6; ++mi)
                av[mi] = *(const float4*)&alds[(m0 + mi) * AST2 + kk4];
#pragma unroll
            for (int mi = 0; mi < 6; ++mi)
#pragma unroll
                for (int nn = 0; nn < 8; ++nn)
                    acc[mi][nn] += av[mi].x * bv[nn].x + av[mi].y * bv[nn].y +
                                   av[mi].z * bv[nn].z + av[mi].w * bv[nn].w;
        }
        __syncthreads();
    }

#pragma unroll
    for (int mi = 0; mi < 6; ++mi) {
        float* row = part + ((size_t)(m0 + mi) * KSPLIT + by) * M_ROWS + j0;
#pragma unroll
        for (int nn = 0; nn < 8; ++nn)
            row[tx + nn * 8] = acc[mi][nn];
    }
}

// ---------------- K3: finalize d2 + masked argmax/argmin ----------------
__global__ void select_kernel(const float* __restrict__ part,
                              const float* __restrict__ fnp,
                              const float* __restrict__ cnp,
                              const int* __restrict__ labels,
                              int* __restrict__ pinds,
                              int* __restrict__ ninds) {
    const int c = blockIdx.x;
    const int tid = threadIdx.x;
    const int anchor = labels[c * KG];

    float cn = 0.f;
#pragma unroll
    for (int b = 0; b < 4; ++b) cn += cnp[b * NC + c];

    float bestp = -INFINITY; int bpi = 1 << 30;
    float bestn =  INFINITY; int bni = 1 << 30;

    const float* pc = part + (size_t)c * KSPLIT * M_ROWS;
    for (int j = tid; j < M_ROWS; j += 256) {
        float dot = 0.f;
#pragma unroll
        for (int p = 0; p < KSPLIT; ++p)
            dot += pc[(size_t)p * M_ROWS + j];
        float fn = 0.f;
#pragma unroll
        for (int b = 0; b < 4; ++b) fn += fnp[b * M_ROWS + j];
        const float d2 = cn + fn - 2.f * dot;
        const bool pos = (labels[j] == anchor);
        if (pos) {
            if (d2 > bestp || (d2 == bestp && j < bpi)) { bestp = d2; bpi = j; }
        } else {
            if (d2 < bestn || (d2 == bestn && j < bni)) { bestn = d2; bni = j; }
        }
    }

    __shared__ float sv[256];
    __shared__ int   si[256];
    sv[tid] = bestp; si[tid] = bpi; __syncthreads();
    for (int s = 128; s > 0; s >>= 1) {
        if (tid < s) {
            if (sv[tid + s] > sv[tid] ||
                (sv[tid + s] == sv[tid] && si[tid + s] < si[tid])) {
                sv[tid] = sv[tid + s]; si[tid] = si[tid + s];
            }
        }
        __syncthreads();
    }
    if (tid == 0) pinds[c] = si[0];
    __syncthreads();
    sv[tid] = bestn; si[tid] = bni; __syncthreads();
    for (int s = 128; s > 0; s >>= 1) {
        if (tid < s) {
            if (sv[tid + s] < sv[tid] ||
                (sv[tid + s] == sv[tid] && si[tid + s] < si[tid])) {
                sv[tid] = sv[tid + s]; si[tid] = si[tid + s];
            }
        }
        __syncthreads();
    }
    if (tid == 0) ninds[c] = si[0];
}

// ---------------- K4: local stripe distances + DP ----------------
__global__ void local_kernel(const float* __restrict__ centers,
                             const float* __restrict__ localf,
                             const int* __restrict__ pinds,
                             const int* __restrict__ ninds,
                             float* __restrict__ res) { // [2][96]
    const int c = blockIdx.x;
    const int which = blockIdx.y;
    const int tid = threadIdx.x;
    const int idx = (which == 0) ? pinds[c] : ninds[c];

    __shared__ float xl[NS * 1028];
    __shared__ float yl[NS * 1032];
    __shared__ float sred[256];
    __shared__ float dmat[64];
    __shared__ float xx[8], yy[8], xyv[64];

#pragma unroll
    for (int it = 0; it < 8; ++it) {
        const int q = tid + it * 256;
        const float4 v = *(const float4*)&centers[(size_t)c * FD + q * 4];
        const int i = q >> 8;
        const int d = (q * 4) & 1023;
        *(float4*)&xl[i * 1028 + d] = v;

        const float4 w = *(const float4*)&localf[(size_t)idx * FD + q * 4];
        const int jb = (q * 4) & 7;
        const int dd = q >> 1;
        yl[(jb + 0) * 1032 + dd] = w.x;
        yl[(jb + 1) * 1032 + dd] = w.y;
        yl[(jb + 2) * 1032 + dd] = w.z;
        yl[(jb + 3) * 1032 + dd] = w.w;
    }
    __syncthreads();

    const int p = tid >> 2, c4 = tid & 3;
    const int i = p >> 3, j = p & 7;
    float s = 0.f;
    for (int t = 0; t < 64; ++t) {
        const int d = c4 * 4 + t * 16;
        const float4 xv = *(const float4*)&xl[i * 1028 + d];
        const float4 yv = *(const float4*)&yl[j * 1032 + d];
        s += xv.x * yv.x + xv.y * yv.y + xv.z * yv.z + xv.w * yv.w;
    }
    sred[tid] = s;
    __syncthreads();
    if (tid < 64)
        xyv[tid] = sred[tid * 4] + sred[tid * 4 + 1] + sred[tid * 4 + 2] + sred[tid * 4 + 3];

    float s2 = 0.f;
    if (tid < 64) {
        const int r = tid >> 2;
        const float* base = (r < 8) ? &xl[r * 1028] : &yl[(r - 8) * 1032];
        for (int t = 0; t < 64; ++t) {
            const int d = c4 * 4 + t * 16;
            const float4 v = *(const float4*)&base[d];
            s2 += v.x * v.x + v.y * v.y + v.z * v.z + v.w * v.w;
        }
    }
    __syncthreads();
    sred[tid] = s2;
    __syncthreads();
    if (tid < 16) {
        const float v = sred[tid * 4] + sred[tid * 4 + 1] + sred[tid * 4 + 2] + sred[tid * 4 + 3];
        if (tid < 8) xx[tid] = v; else yy[tid - 8] = v;
    }
    __syncthreads();

    if (tid < 64) {
        const float d2 = xx[i] + yy[j] - 2.f * xyv[tid];
        const float d = sqrtf(fmaxf(d2, 1e-12f));
        dmat[tid] = tanhf(0.5f * d);
    }
    __syncthreads();

    if (tid == 0) {
        float prev[8], cur[8];
        cur[0] = dmat[0];
#pragma unroll
        for (int jj = 1; jj < 8; ++jj) cur[jj] = cur[jj - 1] + dmat[jj];
        for (int ii = 1; ii < 8; ++ii) {
#pragma unroll
            for (int jj = 0; jj < 8; ++jj) prev[jj] = cur[jj];
            cur[0] = prev[0] + dmat[ii * 8];
#pragma unroll
            for (int jj = 1; jj < 8; ++jj)
                cur[jj] = fminf(prev[jj], cur[jj - 1]) + dmat[ii * 8 + jj];
        }
        res[which * NC + c] = cur[7];
    }
}

// ---------------- K5: mean(relu(ap - an + margin)) ----------------
__global__ void loss_kernel(const float* __restrict__ res, float* __restrict__ out) {
    const int tid = threadIdx.x; // 128
    float v = 0.f;
    if (tid < NC) v = fmaxf(res[tid] - res[NC + tid] + MARGIN, 0.f);
#pragma unroll
    for (int off = 32; off > 0; off >>= 1) v += __shfl_down(v, off, 64);
    __shared__ float w2[2];
    const int lane = tid & 63, w = tid >> 6;
    if (lane == 0) w2[w] = v;
    __syncthreads();
    if (tid == 0) out[0] = (w2[0] + w2[1]) * (1.f / NC);
}

extern "C" void kernel_launch(void* const* d_in, const int* in_sizes, int n_in,
                              void* d_out, int out_size, void* d_ws, size_t ws_size,
                              hipStream_t stream) {
    const float* feats  = (const float*)d_in[0];
    const int*   labels = (const int*)d_in[1];
    const float* localf = (const float*)d_in[2];
    float* out = (float*)d_out;

    float* centers = (float*)d_ws;                          // 96*8192
    float* part    = centers + (size_t)NC * FD;             // 96*32*1536
    float* fnp     = part + (size_t)NC * KSPLIT * M_ROWS;   // 4*1536
    float* cnp     = fnp + 4 * M_ROWS;                      // 4*96
    float* res     = cnp + 4 * NC;                          // 2*96
    int*   pinds   = (int*)(res + 2 * NC);                  // 96
    int*   ninds   = pinds + NC;                            // 96

    hipLaunchKernelGGL(centers_kernel, dim3(NC, 4), dim3(256), 0, stream,
                       feats, centers, fnp, cnp);
    hipLaunchKernelGGL(gemm2_kernel, dim3(24 * KSPLIT), dim3(128), 0, stream,
                       centers, feats, part);
    hipLaunchKernelGGL(select_kernel, dim3(NC), dim3(256), 0, stream,
                       part, fnp, cnp, labels, pinds, ninds);
    hipLaunchKernelGGL(local_kernel, dim3(NC, 2), dim3(256), 0, stream,
                       centers, localf, pinds, ninds, res);
    hipLaunchKernelGGL(loss_kernel, dim3(1), dim3(128), 0, stream, res, out);
}